// Round 1
// baseline (56.873 us; speedup 1.0000x reference)
//
#include <hip/hip_runtime.h>

// RoPE, interleaved-pair convention:
//   x viewed as [..., 64, 2]; y0 = x0*cos - x1*sin; y1 = x0*sin + x1*cos
// x: [32, 8192, 128] f32, token_positions: [32, 8192] int32 (harness casts),
// sin/cos: [8192, 64] f32. Memory-bound: ~268 MiB HBM -> ~45us floor.

__global__ __launch_bounds__(256) void rope_kernel(
    const float* __restrict__ x,
    const int* __restrict__ pos,
    const float* __restrict__ sin_t,
    const float* __restrict__ cos_t,
    float* __restrict__ out,
    int n4)  // total float4 count = B*S*128/4
{
    int i = blockIdx.x * blockDim.x + threadIdx.x;
    const int stride = gridDim.x * blockDim.x;
    const float4* __restrict__ x4 = reinterpret_cast<const float4*>(x);
    const float2* __restrict__ s2 = reinterpret_cast<const float2*>(sin_t);
    const float2* __restrict__ c2 = reinterpret_cast<const float2*>(cos_t);
    float4* __restrict__ o4 = reinterpret_cast<float4*>(out);

    for (; i < n4; i += stride) {
        const int row = i >> 5;        // 32 float4 per 128-elem row
        const int d4  = i & 31;        // float4 index within row -> pairs (2*d4, 2*d4+1)
        const int p   = pos[row];      // sorted per batch row -> cached, wave-redundant
        const int tix = (p << 5) + d4; // p*32 + d4 into [8192][32] float2 table

        const float4 xv = x4[i];
        const float2 sv = s2[tix];
        const float2 cv = c2[tix];

        float4 yv;
        yv.x = xv.x * cv.x - xv.y * sv.x;
        yv.y = xv.x * sv.x + xv.y * cv.x;
        yv.z = xv.z * cv.y - xv.w * sv.y;
        yv.w = xv.z * sv.y + xv.w * cv.y;
        o4[i] = yv;
    }
}

extern "C" void kernel_launch(void* const* d_in, const int* in_sizes, int n_in,
                              void* d_out, int out_size, void* d_ws, size_t ws_size,
                              hipStream_t stream) {
    const float* x     = (const float*)d_in[0];
    const int*   pos   = (const int*)d_in[1];
    const float* sin_t = (const float*)d_in[2];
    const float* cos_t = (const float*)d_in[3];
    float* out = (float*)d_out;

    const int n4 = out_size / 4;           // 8,388,608
    const int block = 256;
    int grid = (n4 + block - 1) / block;
    if (grid > 2048) grid = 2048;          // grid-stride the rest (G11)
    rope_kernel<<<grid, block, 0, stream>>>(x, pos, sin_t, cos_t, out, n4);
}

// Round 3
// 56.821 us; speedup vs baseline: 1.0009x; 1.0009x over previous
//
#include <hip/hip_runtime.h>

// RoPE interleaved-pair: y0 = x0*cos - x1*sin; y1 = x0*sin + x1*cos
// x: [32,8192,128] f32; pos: [32,8192] i32 (sorted per row); sin/cos: [8192,64] f32.
// Memory-bound (~256 MiB compulsory). Strategy: 4 independent chains/thread,
// batched load issue for MLP; nt loads/stores for streaming data so the
// 4 MiB tables stay L2-resident. Use clang ext_vector types (HIP float4
// is rejected by __builtin_nontemporal_*).

typedef float vfloat4 __attribute__((ext_vector_type(4)));
typedef float vfloat2 __attribute__((ext_vector_type(2)));

#define UNROLL 4

__global__ __launch_bounds__(256) void rope_kernel(
    const float* __restrict__ x,
    const int* __restrict__ pos,
    const float* __restrict__ sin_t,
    const float* __restrict__ cos_t,
    float* __restrict__ out,
    int n4)  // total float4 count
{
    const int tid = blockIdx.x * blockDim.x + threadIdx.x;
    const int nthreads = gridDim.x * blockDim.x;

    const vfloat4* __restrict__ x4 = reinterpret_cast<const vfloat4*>(x);
    const vfloat2* __restrict__ s2 = reinterpret_cast<const vfloat2*>(sin_t);
    const vfloat2* __restrict__ c2 = reinterpret_cast<const vfloat2*>(cos_t);
    vfloat4* __restrict__ o4 = reinterpret_cast<vfloat4*>(out);

    int idx[UNROLL];
    int ci[UNROLL];     // clamped index: loads always in-bounds, store guarded
    #pragma unroll
    for (int u = 0; u < UNROLL; ++u) {
        idx[u] = tid + u * nthreads;
        ci[u]  = idx[u] < n4 ? idx[u] : 0;
    }

    // batch 1: all position loads (independent, L1/L2-hit, wave-redundant)
    int p[UNROLL];
    #pragma unroll
    for (int u = 0; u < UNROLL; ++u)
        p[u] = pos[ci[u] >> 5];           // 32 float4 per 128-elem row

    // batch 2: all x loads (streaming -> nontemporal)
    vfloat4 xv[UNROLL];
    #pragma unroll
    for (int u = 0; u < UNROLL; ++u)
        xv[u] = __builtin_nontemporal_load(&x4[ci[u]]);

    // batch 3: all table gathers (want these cached -> regular loads)
    vfloat2 sv[UNROLL], cv[UNROLL];
    #pragma unroll
    for (int u = 0; u < UNROLL; ++u) {
        const int tix = (p[u] << 5) + (ci[u] & 31);  // p*32 + d4, [8192][32] float2
        sv[u] = s2[tix];
        cv[u] = c2[tix];
    }

    // compute + store (streaming -> nontemporal)
    #pragma unroll
    for (int u = 0; u < UNROLL; ++u) {
        if (idx[u] < n4) {
            vfloat4 yv;
            yv.x = xv[u].x * cv[u].x - xv[u].y * sv[u].x;
            yv.y = xv[u].x * sv[u].x + xv[u].y * cv[u].x;
            yv.z = xv[u].z * cv[u].y - xv[u].w * sv[u].y;
            yv.w = xv[u].z * sv[u].y + xv[u].w * cv[u].y;
            __builtin_nontemporal_store(yv, &o4[idx[u]]);
        }
    }
}

extern "C" void kernel_launch(void* const* d_in, const int* in_sizes, int n_in,
                              void* d_out, int out_size, void* d_ws, size_t ws_size,
                              hipStream_t stream) {
    const float* x     = (const float*)d_in[0];
    const int*   pos   = (const int*)d_in[1];
    const float* sin_t = (const float*)d_in[2];
    const float* cos_t = (const float*)d_in[3];
    float* out = (float*)d_out;

    const int n4 = out_size / 4;                 // 8,388,608
    const int block = 256;
    const int per_block = block * UNROLL;        // 1024 float4 per block
    const int grid = (n4 + per_block - 1) / per_block;  // 8192 -> exact, no tail
    rope_kernel<<<grid, block, 0, stream>>>(x, pos, sin_t, cos_t, out, n4);
}

// Round 4
// 48.604 us; speedup vs baseline: 1.1701x; 1.1691x over previous
//
#include <hip/hip_runtime.h>

// RoPE interleaved-pair: y0 = x0*cos - x1*sin; y1 = x0*sin + x1*cos
// x: [32,8192,128] f32; pos: [32,8192] i32 (sorted per row); sin/cos: [8192,64] f32.
// Memory-bound (~268 MB compulsory -> 42.6us @ 6.29 TB/s copy ceiling).
// R4 theory: stream locality. Each wave owns a contiguous 4KB span; its 4
// independent unrolled accesses are adjacent 1KB wave-chunks, so the DRAM
// sees few, long streams instead of ~100K scattered ones. Regular loads for
// x (keep L3 reuse), nontemporal stores (protect L2-resident tables).

typedef float vfloat4 __attribute__((ext_vector_type(4)));
typedef float vfloat2 __attribute__((ext_vector_type(2)));

#define UNROLL 4

__global__ __launch_bounds__(256) void rope_kernel(
    const float* __restrict__ x,
    const int* __restrict__ pos,
    const float* __restrict__ sin_t,
    const float* __restrict__ cos_t,
    float* __restrict__ out)
{
    const int lane = threadIdx.x & 63;
    const int wave = threadIdx.x >> 6;
    // block owns 1024 consecutive float4 (16KB); wave owns contiguous 4KB.
    const int base = blockIdx.x * 1024 + wave * 256 + lane;

    const vfloat4* __restrict__ x4 = reinterpret_cast<const vfloat4*>(x);
    const vfloat2* __restrict__ s2 = reinterpret_cast<const vfloat2*>(sin_t);
    const vfloat2* __restrict__ c2 = reinterpret_cast<const vfloat2*>(cos_t);
    vfloat4* __restrict__ o4 = reinterpret_cast<vfloat4*>(out);

    int idx[UNROLL];
    #pragma unroll
    for (int u = 0; u < UNROLL; ++u)
        idx[u] = base + u * 64;          // adjacent 1KB wave-chunks

    // batch 1: position loads (2 rows per wave-chunk, broadcast within 32 lanes)
    int p[UNROLL];
    #pragma unroll
    for (int u = 0; u < UNROLL; ++u)
        p[u] = pos[idx[u] >> 5];         // 32 float4 per 128-elem row

    // batch 2: x loads (regular -> L2/L3 assisted)
    vfloat4 xv[UNROLL];
    #pragma unroll
    for (int u = 0; u < UNROLL; ++u)
        xv[u] = x4[idx[u]];

    // batch 3: table gathers (L1/L2-hit)
    vfloat2 sv[UNROLL], cv[UNROLL];
    #pragma unroll
    for (int u = 0; u < UNROLL; ++u) {
        const int tix = (p[u] << 5) + (idx[u] & 31);  // p*32 + d4, [8192][32] float2
        sv[u] = s2[tix];
        cv[u] = c2[tix];
    }

    // compute + nontemporal store
    #pragma unroll
    for (int u = 0; u < UNROLL; ++u) {
        vfloat4 yv;
        yv.x = xv[u].x * cv[u].x - xv[u].y * sv[u].x;
        yv.y = xv[u].x * sv[u].x + xv[u].y * cv[u].x;
        yv.z = xv[u].z * cv[u].y - xv[u].w * sv[u].y;
        yv.w = xv[u].z * sv[u].y + xv[u].w * cv[u].y;
        __builtin_nontemporal_store(yv, &o4[idx[u]]);
    }
}

extern "C" void kernel_launch(void* const* d_in, const int* in_sizes, int n_in,
                              void* d_out, int out_size, void* d_ws, size_t ws_size,
                              hipStream_t stream) {
    const float* x     = (const float*)d_in[0];
    const int*   pos   = (const int*)d_in[1];
    const float* sin_t = (const float*)d_in[2];
    const float* cos_t = (const float*)d_in[3];
    float* out = (float*)d_out;

    const int n4 = out_size / 4;                 // 8,388,608 (exact multiple of 1024)
    const int block = 256;
    const int grid = n4 / (block * UNROLL);      // 8192 blocks, no tail
    rope_kernel<<<grid, block, 0, stream>>>(x, pos, sin_t, cos_t, out);
}

// Round 5
// 47.466 us; speedup vs baseline: 1.1982x; 1.0240x over previous
//
#include <hip/hip_runtime.h>

// RoPE interleaved-pair: y0 = x0*cos - x1*sin; y1 = x0*sin + x1*cos
// x: [32,8192,128] f32; pos: [32,8192] i32 (sorted per row); sin/cos: [8192,64] f32.
// Memory-bound (~268 MB compulsory -> ~42.6us @ 6.29 TB/s copy ceiling).
// R4 (48.6us): contiguous 4KB/wave spans. R5: extend to 8KB/wave (UNROLL 8)
// for longer DRAM streams + genuinely more per-wave loads in flight
// (R4 compiled to VGPR=20 -> chains were serialized).
// Regular loads for x (L3 retention), nontemporal stores for out.

typedef float vfloat4 __attribute__((ext_vector_type(4)));
typedef float vfloat2 __attribute__((ext_vector_type(2)));

#define UNROLL 8

__global__ __launch_bounds__(256) void rope_kernel(
    const float* __restrict__ x,
    const int* __restrict__ pos,
    const float* __restrict__ sin_t,
    const float* __restrict__ cos_t,
    float* __restrict__ out)
{
    const int lane = threadIdx.x & 63;
    const int wave = threadIdx.x >> 6;
    // block owns 2048 consecutive float4 (32KB); wave owns contiguous 8KB.
    const int base = blockIdx.x * (256 * UNROLL) + wave * (64 * UNROLL) + lane;

    const vfloat4* __restrict__ x4 = reinterpret_cast<const vfloat4*>(x);
    const vfloat2* __restrict__ s2 = reinterpret_cast<const vfloat2*>(sin_t);
    const vfloat2* __restrict__ c2 = reinterpret_cast<const vfloat2*>(cos_t);
    vfloat4* __restrict__ o4 = reinterpret_cast<vfloat4*>(out);

    int idx[UNROLL];
    #pragma unroll
    for (int u = 0; u < UNROLL; ++u)
        idx[u] = base + u * 64;          // adjacent 1KB wave-chunks

    // batch 1: position loads (2 rows per wave-chunk, sorted -> adjacent)
    int p[UNROLL];
    #pragma unroll
    for (int u = 0; u < UNROLL; ++u)
        p[u] = pos[idx[u] >> 5];         // 32 float4 per 128-elem row

    // batch 2: x loads (regular -> L3-assisted)
    vfloat4 xv[UNROLL];
    #pragma unroll
    for (int u = 0; u < UNROLL; ++u)
        xv[u] = x4[idx[u]];

    // batch 3: table gathers (L1/L2-hit; nearby rows due to sorted pos)
    vfloat2 sv[UNROLL], cv[UNROLL];
    #pragma unroll
    for (int u = 0; u < UNROLL; ++u) {
        const int tix = (p[u] << 5) + (idx[u] & 31);  // p*32 + d4, [8192][32] float2
        sv[u] = s2[tix];
        cv[u] = c2[tix];
    }

    // compute + nontemporal store
    #pragma unroll
    for (int u = 0; u < UNROLL; ++u) {
        vfloat4 yv;
        yv.x = xv[u].x * cv[u].x - xv[u].y * sv[u].x;
        yv.y = xv[u].x * sv[u].x + xv[u].y * cv[u].x;
        yv.z = xv[u].z * cv[u].y - xv[u].w * sv[u].y;
        yv.w = xv[u].z * sv[u].y + xv[u].w * cv[u].y;
        __builtin_nontemporal_store(yv, &o4[idx[u]]);
    }
}

extern "C" void kernel_launch(void* const* d_in, const int* in_sizes, int n_in,
                              void* d_out, int out_size, void* d_ws, size_t ws_size,
                              hipStream_t stream) {
    const float* x     = (const float*)d_in[0];
    const int*   pos   = (const int*)d_in[1];
    const float* sin_t = (const float*)d_in[2];
    const float* cos_t = (const float*)d_in[3];
    float* out = (float*)d_out;

    const int n4 = out_size / 4;                 // 8,388,608 (multiple of 2048)
    const int block = 256;
    const int grid = n4 / (block * UNROLL);      // 4096 blocks, no tail
    rope_kernel<<<grid, block, 0, stream>>>(x, pos, sin_t, cos_t, out);
}

// Round 7
// 47.461 us; speedup vs baseline: 1.1983x; 1.0001x over previous
//
#include <hip/hip_runtime.h>

// RoPE interleaved-pair: y0 = x0*cos - x1*sin; y1 = x0*sin + x1*cos
// x: [32,8192,128] f32; pos: [32,8192] i32 (sorted); sin/cos: [8192,64] f32.
// Memory-bound: 268 MB compulsory -> 42.6us @ 6.29 TB/s copy ceiling.
// R5 (47.5us, 90% of ceiling): 8KB contiguous span per wave, nt stores.
// R6 (sc0 sc1 store bypass): CORRECTNESS FAIL - L2 coherence violation vs
//   harness memset/readback. Do not bypass coherence on stores.
// R7: single change vs R5 - span 8KB -> 16KB per wave (UNROLL 16),
//   2048 blocks = exactly one full device residency, no tail.

typedef float vfloat4 __attribute__((ext_vector_type(4)));
typedef float vfloat2 __attribute__((ext_vector_type(2)));

#define UNROLL 16

__global__ __launch_bounds__(256) void rope_kernel(
    const float* __restrict__ x,
    const int* __restrict__ pos,
    const float* __restrict__ sin_t,
    const float* __restrict__ cos_t,
    float* __restrict__ out)
{
    const int lane = threadIdx.x & 63;
    const int wave = threadIdx.x >> 6;
    // block owns 4096 consecutive float4 (64KB); wave owns contiguous 16KB.
    const int base = blockIdx.x * (256 * UNROLL) + wave * (64 * UNROLL) + lane;

    const vfloat4* __restrict__ x4 = reinterpret_cast<const vfloat4*>(x);
    const vfloat2* __restrict__ s2 = reinterpret_cast<const vfloat2*>(sin_t);
    const vfloat2* __restrict__ c2 = reinterpret_cast<const vfloat2*>(cos_t);
    vfloat4* __restrict__ o4 = reinterpret_cast<vfloat4*>(out);

    int idx[UNROLL];
    #pragma unroll
    for (int u = 0; u < UNROLL; ++u)
        idx[u] = base + u * 64;          // adjacent 1KB wave-chunks

    // position loads (sorted -> adjacent rows, L1/L2-hit)
    int p[UNROLL];
    #pragma unroll
    for (int u = 0; u < UNROLL; ++u)
        p[u] = pos[idx[u] >> 5];         // 32 float4 per 128-elem row

    // x loads (regular -> L3 retention across replays)
    vfloat4 xv[UNROLL];
    #pragma unroll
    for (int u = 0; u < UNROLL; ++u)
        xv[u] = x4[idx[u]];

    // table gathers (L1/L2-hit)
    vfloat2 sv[UNROLL], cv[UNROLL];
    #pragma unroll
    for (int u = 0; u < UNROLL; ++u) {
        const int tix = (p[u] << 5) + (idx[u] & 31);  // p*32 + d4, [8192][32] float2
        sv[u] = s2[tix];
        cv[u] = c2[tix];
    }

    // compute + nontemporal (coherent, LRU-hint) store
    #pragma unroll
    for (int u = 0; u < UNROLL; ++u) {
        vfloat4 yv;
        yv.x = xv[u].x * cv[u].x - xv[u].y * sv[u].x;
        yv.y = xv[u].x * sv[u].x + xv[u].y * cv[u].x;
        yv.z = xv[u].z * cv[u].y - xv[u].w * sv[u].y;
        yv.w = xv[u].z * sv[u].y + xv[u].w * cv[u].y;
        __builtin_nontemporal_store(yv, &o4[idx[u]]);
    }
}

extern "C" void kernel_launch(void* const* d_in, const int* in_sizes, int n_in,
                              void* d_out, int out_size, void* d_ws, size_t ws_size,
                              hipStream_t stream) {
    const float* x     = (const float*)d_in[0];
    const int*   pos   = (const int*)d_in[1];
    const float* sin_t = (const float*)d_in[2];
    const float* cos_t = (const float*)d_in[3];
    float* out = (float*)d_out;

    const int n4 = out_size / 4;                 // 8,388,608 (multiple of 4096)
    const int block = 256;
    const int grid = n4 / (block * UNROLL);      // 2048 blocks, no tail
    rope_kernel<<<grid, block, 0, stream>>>(x, pos, sin_t, cos_t, out);
}